// Round 9
// baseline (338.358 us; speedup 1.0000x reference)
//
#include <hip/hip_runtime.h>
#include <hip/hip_bf16.h>
#include <stdint.h>

// Problem dims (fixed by the reference)
#define DM 768
#define DI 1536
#define DSTATE 16
#define RNK 48
#define BB 2
#define LL 1024
#define ML (BB * LL)  // 2048 rows (b*l flattened)

// segmented scan config
#define NSEG 32
#define SEGL (LL / NSEG)   // 32

// proj output layout: [B(16) | C(16) | delta_arg(1536)] -> N=1568, pad to 1664
#define PN 1664
#define PLD 1664

typedef unsigned short u16;
typedef __bf16 bf16x8 __attribute__((ext_vector_type(8)));
typedef float f32x4 __attribute__((ext_vector_type(4)));

struct __align__(8) u16x4_t { u16 x, y, z, w; };

__device__ __forceinline__ float b2f(u16 u) {
  union { uint32_t i; float f; } v; v.i = ((uint32_t)u) << 16; return v.f;
}
__device__ __forceinline__ u16 f2b(float f) {
  union { float f; uint32_t i; } v; v.f = f;
  uint32_t r = v.i + 0x7FFFu + ((v.i >> 16) & 1u);  // RNE
  return (u16)(r >> 16);
}
__device__ __forceinline__ float silu_f(float x) { return x / (1.f + __expf(-x)); }
// fast softplus: max(s,0) + log(1+exp(-|s|)); HW exp/log only (~1e-7 abs err)
__device__ __forceinline__ float softplus_f(float s) {
  return fmaxf(s, 0.f) + __logf(1.f + __expf(-fabsf(s)));
}
__device__ __forceinline__ u16x4_t cvt4(float4 v) {
  u16x4_t o; o.x = f2b(v.x); o.y = f2b(v.y); o.z = f2b(v.z); o.w = f2b(v.w); return o;
}

// ---------------------------------------------------------------------------
// Fused fp32->bf16 conversion of GEMM operands + proj-weight partial fill.
// cat rows (of the 1664-row B-matrix): [0..15]=W_B, [16..31]=W_C,
// [1568..1663]=0. Rows 32..1567 (composite M) are written by mcomp_kernel.
// The 128 rows handled here are indexed 0..127 -> physical row +1536 if >=32.
// ---------------------------------------------------------------------------
#define SEG_X    (ML * DM / 4)
#define SEG_W    (DI * DM / 4)
#define SEG_CAT  (128 * DI / 4)
__global__ __launch_bounds__(256) void convert_kernel(
    const float4* __restrict__ x, const float4* __restrict__ wis,
    const float4* __restrict__ wig, const float4* __restrict__ wout,
    const float* __restrict__ W_B, const float* __restrict__ W_C,
    const float* __restrict__ W_B_b, const float* __restrict__ W_C_b,
    u16x4_t* __restrict__ xb, u16x4_t* __restrict__ wisb,
    u16x4_t* __restrict__ wigb, u16x4_t* __restrict__ woutb,
    u16x4_t* __restrict__ wcf, u16x4_t* __restrict__ wcb)
{
  int idx = blockIdx.x * 256 + threadIdx.x;
  if (idx < SEG_X) { xb[idx] = cvt4(x[idx]); return; }
  idx -= SEG_X;
  if (idx < SEG_W) { wisb[idx] = cvt4(wis[idx]); return; }
  idx -= SEG_W;
  if (idx < SEG_W) { wigb[idx] = cvt4(wig[idx]); return; }
  idx -= SEG_W;
  if (idx < SEG_W) { woutb[idx] = cvt4(wout[idx]); return; }
  idx -= SEG_W;
  int dir = idx / SEG_CAT;
  int rem = idx % SEG_CAT;
  int row = rem / (DI / 4), k4 = rem % (DI / 4);
  const float* src = nullptr;
  if (row < 16)      src = (dir ? W_B_b : W_B) + (size_t)row * DI + k4 * 4;
  else if (row < 32) src = (dir ? W_C_b : W_C) + (size_t)(row - 16) * DI + k4 * 4;
  int prow = (row < 32) ? row : row + 1536;           // zeros land at 1568..1663
  u16x4_t o;
  if (src) o = cvt4(*(const float4*)src);
  else { o.x = 0; o.y = 0; o.z = 0; o.w = 0; }
  (dir ? wcb : wcf)[(size_t)prow * (DI / 4) + k4] = o;
}

// ---------------------------------------------------------------------------
// Composite delta weight: M[d,k] = sum_r dtW[d,r] * W_dt[r,k], bf16 into
// wcat rows 32+d. (delta_arg = xc @ M^T then softplus — folds the former
// delta_kernel into the MFMA proj GEMM.)
// ---------------------------------------------------------------------------
__global__ __launch_bounds__(256) void mcomp_kernel(
    const float* __restrict__ W_dt, const float* __restrict__ dtW,
    const float* __restrict__ W_dt_b, const float* __restrict__ dtW_b,
    u16* __restrict__ wcf, u16* __restrict__ wcb)
{
  const int dir = blockIdx.z;
  const float* Wd = dir ? W_dt_b : W_dt;   // (RNK, DI)
  const float* Dw = dir ? dtW_b : dtW;     // (DI, RNK)
  u16* wcat = dir ? wcb : wcf;
  const int d0 = blockIdx.y * 16;
  const int k = blockIdx.x * 256 + threadIdx.x;

  __shared__ float dtw_sh[16][RNK];        // 3 KB
  for (int i = threadIdx.x; i < 16 * RNK; i += 256) {
    int dd = i / RNK, r = i % RNK;
    dtw_sh[dd][r] = Dw[(size_t)(d0 + dd) * RNK + r];
  }
  __syncthreads();

  float acc[16];
#pragma unroll
  for (int dd = 0; dd < 16; ++dd) acc[dd] = 0.f;
  for (int r = 0; r < RNK; ++r) {
    float wv = Wd[(size_t)r * DI + k];
#pragma unroll
    for (int dd = 0; dd < 16; ++dd) acc[dd] += dtw_sh[dd][r] * wv;
  }
#pragma unroll
  for (int dd = 0; dd < 16; ++dd)
    wcat[(size_t)(32 + d0 + dd) * DI + k] = f2b(acc[dd]);
}

// ---------------------------------------------------------------------------
// Generic bf16 GEMM (validated rounds 3/4/6): C = A (MxK) @ B^T (NxK).
// 128x128 tile, 4 waves, 16x16x32 MFMA, uint4 staging.
// ---------------------------------------------------------------------------
__global__ __launch_bounds__(256) void gemm_bt(
    const u16* __restrict__ A, const u16* __restrict__ B0,
    const u16* __restrict__ B1, int Nsplit,
    void* __restrict__ Cout, int M, int N, int K, int ldc, int epi,
    const u16* __restrict__ A2, const u16* __restrict__ B2,
    void* __restrict__ C2)
{
  if (blockIdx.z) { A = A2; B0 = B2; Cout = C2; }
  __shared__ alignas(16) u16 As[128 * 32];
  __shared__ alignas(16) u16 Bs[128 * 32];
  const int tid = threadIdx.x;
  const int wave = tid >> 6, lane = tid & 63;
  const int bm = blockIdx.y * 128;
  const int bn = blockIdx.x * 128;

  const u16* Bmat = B0;
  int ncol0 = bn;
  int epi_l = epi;
  if (B1 != nullptr && bn >= Nsplit) { Bmat = B1; ncol0 = bn - Nsplit; epi_l = 1; }

  const int c0 = tid, c1 = tid + 256;
  const u16* gA0 = A + (size_t)(bm + (c0 >> 2)) * K + (c0 & 3) * 8;
  const u16* gA1 = A + (size_t)(bm + (c1 >> 2)) * K + (c1 & 3) * 8;
  const u16* gB0 = Bmat + (size_t)(ncol0 + (c0 >> 2)) * K + (c0 & 3) * 8;
  const u16* gB1 = Bmat + (size_t)(ncol0 + (c1 >> 2)) * K + (c1 & 3) * 8;
  uint4* lA0 = (uint4*)&As[c0 * 8]; uint4* lA1 = (uint4*)&As[c1 * 8];
  uint4* lB0 = (uint4*)&Bs[c0 * 8]; uint4* lB1 = (uint4*)&Bs[c1 * 8];

  const int wm = (wave & 1) * 64, wn = (wave >> 1) * 64;
  const int rl = lane & 15, q = lane >> 4;

  f32x4 acc[4][4];
#pragma unroll
  for (int i = 0; i < 4; ++i)
#pragma unroll
    for (int j = 0; j < 4; ++j) acc[i][j] = (f32x4){0.f, 0.f, 0.f, 0.f};

  const bf16x8* AsV = (const bf16x8*)As;
  const bf16x8* BsV = (const bf16x8*)Bs;

  for (int k0 = 0; k0 < K; k0 += 32) {
    uint4 ra0 = *(const uint4*)(gA0 + k0);
    uint4 ra1 = *(const uint4*)(gA1 + k0);
    uint4 rb0 = *(const uint4*)(gB0 + k0);
    uint4 rb1 = *(const uint4*)(gB1 + k0);
    *lA0 = ra0; *lA1 = ra1; *lB0 = rb0; *lB1 = rb1;
    __syncthreads();
    bf16x8 af[4], bfv[4];
#pragma unroll
    for (int s = 0; s < 4; ++s) {
      af[s]  = AsV[(wm + s * 16 + rl) * 4 + q];
      bfv[s] = BsV[(wn + s * 16 + rl) * 4 + q];
    }
#pragma unroll
    for (int i = 0; i < 4; ++i)
#pragma unroll
      for (int j = 0; j < 4; ++j)
        acc[i][j] = __builtin_amdgcn_mfma_f32_16x16x32_bf16(af[i], bfv[j], acc[i][j], 0, 0, 0);
    __syncthreads();
  }

#pragma unroll
  for (int i = 0; i < 4; ++i) {
#pragma unroll
    for (int j = 0; j < 4; ++j) {
#pragma unroll
      for (int r = 0; r < 4; ++r) {
        int row = bm + wm + i * 16 + q * 4 + r;
        int col = bn + wn + j * 16 + rl;
        float v = acc[i][j][r];
        if (epi_l == 1) v = silu_f(v);
        if (epi == 2) ((float*)Cout)[(size_t)row * ldc + col] = v;
        else          ((u16*)Cout)[(size_t)row * ldc + col] = f2b(v);
      }
    }
  }
}

// ---------------------------------------------------------------------------
// Causal depthwise conv (K=4, fp32 weights) + SiLU, fwd + reversed.
// ---------------------------------------------------------------------------
__global__ void conv_kernel(
    const u16* __restrict__ xsg,
    const float* __restrict__ cw, const float* __restrict__ cb,
    const float* __restrict__ cwb, const float* __restrict__ cbb,
    u16* __restrict__ xc, u16* __restrict__ xcb)
{
  int idx = blockIdx.x * 256 + threadIdx.x;      // over ML*DI
  int d = idx % DI;
  int row = idx / DI;
  int l = row % LL, b = row / LL;
  const u16* base = xsg + (size_t)b * LL * 3072 + d;

  float4 wf = *(const float4*)(cw + d * 4);
  float4 wb = *(const float4*)(cwb + d * 4);
  float wfk[4] = {wf.x, wf.y, wf.z, wf.w};
  float wbk[4] = {wb.x, wb.y, wb.z, wb.w};

  float accf = cb[d];
  float accb = cbb[d];
#pragma unroll
  for (int k = 0; k < 4; ++k) {
    int ls = l - 3 + k;
    if (ls >= 0) {
      accf += wfk[k] * b2f(base[(size_t)ls * 3072]);
      accb += wbk[k] * b2f(base[(size_t)(LL - 1 - ls) * 3072]);
    }
  }
  xc[idx]  = f2b(silu_f(accf));
  xcb[idx] = f2b(silu_f(accb));
}

// ---------------------------------------------------------------------------
// Segmented scan, phase A: per (dir,b,seg,d) compute Sdelta and local
// end-state h_local[16] (h_in=0). delta = softplus(proj delta_arg col 32+d).
// ---------------------------------------------------------------------------
__global__ __launch_bounds__(256) void scan_sum(
    const u16* __restrict__ xcf, const u16* __restrict__ xcb,
    const float* __restrict__ pf, const float* __restrict__ pb,
    const float* __restrict__ A_log, const float* __restrict__ A_log_b,
    float* __restrict__ sdl, float* __restrict__ bs)
{
  const int dir = blockIdx.z / NSEG, seg = blockIdx.z % NSEG;
  const u16* xc = dir ? xcb : xcf;
  const float* proj = dir ? pb : pf;
  const float* Al = dir ? A_log_b : A_log;
  const int b = blockIdx.y;
  const int d = blockIdx.x * 256 + threadIdx.x;
  const int l0 = seg * SEGL;

  __shared__ float Bsh[SEGL][16];
  for (int i = threadIdx.x; i < SEGL * 16; i += 256) {
    int l = i >> 4, n = i & 15;
    Bsh[l][n] = proj[((size_t)b * LL + l0 + l) * PLD + n];
  }
  __syncthreads();

  float An[16];
#pragma unroll
  for (int n = 0; n < 16; ++n) An[n] = -__expf(Al[d * 16 + n]);

  float h[16];
#pragma unroll
  for (int n = 0; n < 16; ++n) h[n] = 0.f;
  float S = 0.f;

  const float* dbase = proj + ((size_t)b * LL + l0) * PLD + 32 + d;
  const u16* xbase = xc + ((size_t)b * LL + l0) * DI + d;

  for (int g = 0; g < SEGL; g += 4) {
    float dl4[4], dx4[4];
#pragma unroll
    for (int j = 0; j < 4; ++j) {
      float dv = softplus_f(dbase[(size_t)(g + j) * PLD]);
      float xv = b2f(xbase[(size_t)(g + j) * DI]);
      dl4[j] = dv; dx4[j] = dv * xv;
    }
#pragma unroll
    for (int j = 0; j < 4; ++j) {
      S += dl4[j];
#pragma unroll
      for (int n = 0; n < 16; ++n)
        h[n] = __expf(dl4[j] * An[n]) * h[n] + dx4[j] * Bsh[g + j][n];
    }
  }

  size_t base = (((size_t)dir * BB + b) * NSEG + seg) * DI + d;
  sdl[base] = S;
#pragma unroll
  for (int n = 0; n < 16; ++n) bs[base * 16 + n] = h[n];
}

// ---------------------------------------------------------------------------
// Phase B: compose segment summaries into carry-ins (bs overwritten in place).
// ---------------------------------------------------------------------------
__global__ __launch_bounds__(256) void scan_carry(
    const float* __restrict__ A_log, const float* __restrict__ A_log_b,
    const float* __restrict__ sdl, float* __restrict__ bs)
{
  int idx = blockIdx.x * 256 + threadIdx.x;   // over 2*BB*DI*16
  int n = idx & 15;
  int t = idx >> 4;
  int d = t % DI;
  int b = (t / DI) % BB;
  int dir = t / (DI * BB);
  const float* Al = dir ? A_log_b : A_log;
  float An = -__expf(Al[d * 16 + n]);
  float h = 0.f;
  for (int s = 0; s < NSEG; ++s) {
    size_t base = (((size_t)dir * BB + b) * NSEG + s) * DI + d;
    float S = sdl[base];
    float bv = bs[base * 16 + n];
    bs[base * 16 + n] = h;
    h = __expf(S * An) * h + bv;
  }
}

// ---------------------------------------------------------------------------
// Phase C: redo recurrence from carry-in, compute y.
// ---------------------------------------------------------------------------
__global__ __launch_bounds__(256) void scan_apply(
    const u16* __restrict__ xcf, const u16* __restrict__ xcb,
    const float* __restrict__ pf, const float* __restrict__ pb,
    const float* __restrict__ A_log, const float* __restrict__ A_log_b,
    const float* __restrict__ Dp, const float* __restrict__ Dp_b,
    const float* __restrict__ bs,
    u16* __restrict__ y_f, u16* __restrict__ y_b)
{
  const int dir = blockIdx.z / NSEG, seg = blockIdx.z % NSEG;
  const u16* xc = dir ? xcb : xcf;
  const float* proj = dir ? pb : pf;
  const float* Al = dir ? A_log_b : A_log;
  const float* Dpp = dir ? Dp_b : Dp;
  u16* y = dir ? y_b : y_f;
  const int b = blockIdx.y;
  const int d = blockIdx.x * 256 + threadIdx.x;
  const int l0 = seg * SEGL;

  __shared__ float BCsh[SEGL][32];            // [l][0:16)=B, [16:32)=C
  for (int i = threadIdx.x; i < SEGL * 32; i += 256) {
    int l = i >> 5, j = i & 31;
    BCsh[l][j] = proj[((size_t)b * LL + l0 + l) * PLD + j];
  }
  __syncthreads();

  float An[16];
#pragma unroll
  for (int n = 0; n < 16; ++n) An[n] = -__expf(Al[d * 16 + n]);
  const float Dv = Dpp[d];

  float h[16];
  size_t cbase = (((size_t)dir * BB + b) * NSEG + seg) * DI + d;
#pragma unroll
  for (int n = 0; n < 16; ++n) h[n] = bs[cbase * 16 + n];

  const float* dbase = proj + ((size_t)b * LL + l0) * PLD + 32 + d;
  const u16* xbase = xc + ((size_t)b * LL + l0) * DI + d;
  u16* ybase = y + ((size_t)b * LL + l0) * DI + d;

  for (int g = 0; g < SEGL; g += 4) {
    float dl4[4], xv4[4];
#pragma unroll
    for (int j = 0; j < 4; ++j) {
      dl4[j] = softplus_f(dbase[(size_t)(g + j) * PLD]);
      xv4[j] = b2f(xbase[(size_t)(g + j) * DI]);
    }
#pragma unroll
    for (int j = 0; j < 4; ++j) {
      float dx = dl4[j] * xv4[j];
      float yv = 0.f;
#pragma unroll
      for (int n = 0; n < 16; ++n) {
        h[n] = __expf(dl4[j] * An[n]) * h[n] + dx * BCsh[g + j][n];
        yv += h[n] * BCsh[g + j][16 + n];
      }
      ybase[(size_t)(g + j) * DI] = f2b(yv + Dv * xv4[j]);
    }
  }
}

// ---------------------------------------------------------------------------
// y_comb[l] = 0.5 * silu(z[l]) * (y_f[l] + y_b_rev[L-1-l]); in-place over yf.
// ---------------------------------------------------------------------------
__global__ void combine_kernel(
    const u16* __restrict__ ybr, const u16* __restrict__ xsg, u16* yf)
{
  int idx = blockIdx.x * 256 + threadIdx.x;      // over ML*DI
  int d = idx % DI;
  int row = idx / DI;
  int l = row % LL, b = row / LL;
  float g = b2f(xsg[(size_t)row * 3072 + DI + d]);
  float vb = b2f(ybr[((size_t)b * LL + (LL - 1 - l)) * DI + d]);
  float v = 0.5f * (b2f(yf[idx]) + vb) * g;
  yf[idx] = f2b(v);
}

// ---------------------------------------------------------------------------
extern "C" void kernel_launch(void* const* d_in, const int* in_sizes, int n_in,
                              void* d_out, int out_size, void* d_ws, size_t ws_size,
                              hipStream_t stream)
{
  const float* x       = (const float*)d_in[0];
  const float* Wis     = (const float*)d_in[1];
  const float* Wig     = (const float*)d_in[2];
  const float* conv_w  = (const float*)d_in[3];
  const float* conv_b  = (const float*)d_in[4];
  const float* conv_wb = (const float*)d_in[5];
  const float* conv_bb = (const float*)d_in[6];
  const float* W_dt    = (const float*)d_in[7];
  const float* W_B     = (const float*)d_in[8];
  const float* W_C     = (const float*)d_in[9];
  const float* dtW     = (const float*)d_in[10];
  const float* dtb     = (const float*)d_in[11];
  const float* A_log   = (const float*)d_in[12];
  const float* Dp      = (const float*)d_in[13];
  const float* W_dt_b  = (const float*)d_in[14];
  const float* W_B_b   = (const float*)d_in[15];
  const float* W_C_b   = (const float*)d_in[16];
  const float* dtW_b   = (const float*)d_in[17];
  const float* dtb_b   = (const float*)d_in[18];
  const float* A_log_b = (const float*)d_in[19];
  const float* Dp_b    = (const float*)d_in[20];
  const float* W_out   = (const float*)d_in[21];

  char* ws = (char*)d_ws;
  size_t off = 0;
  auto alloc = [&](size_t bytes) -> char* {
    char* p = ws + off; off += (bytes + 255) & ~(size_t)255; return p;
  };
  u16*   xb    = (u16*)alloc((size_t)ML * DM * 2);
  u16*   wisb  = (u16*)alloc((size_t)DI * DM * 2);
  u16*   wigb  = (u16*)alloc((size_t)DI * DM * 2);
  u16*   woutb = (u16*)alloc((size_t)DM * DI * 2);
  u16*   xsg = (u16*)alloc((size_t)ML * 3072 * 2);     // [xs | silu(z)]
  u16*   xc  = (u16*)alloc((size_t)ML * DI * 2);
  u16*   xcb = (u16*)alloc((size_t)ML * DI * 2);       // reversed space
  u16*   wcf = (u16*)alloc((size_t)PN * DI * 2);       // 5.1 MB (B|C|M|0)
  u16*   wcb = (u16*)alloc((size_t)PN * DI * 2);
  float* pf  = (float*)alloc((size_t)ML * PLD * 4);    // 13.6 MB
  float* pb  = (float*)alloc((size_t)ML * PLD * 4);
  u16*   yf  = (u16*)alloc((size_t)ML * DI * 2);       // later holds combined y
  u16*   ybr = (u16*)alloc((size_t)ML * DI * 2);       // reversed space
  float* sdl = (float*)alloc((size_t)2 * BB * NSEG * DI * 4);
  float* bs  = (float*)alloc((size_t)2 * BB * NSEG * DI * 16 * 4);
  // total ~96 MB

  // 1. fp32->bf16 conversion + proj B/C/zero rows
  const int conv_total = SEG_X + 3 * SEG_W + 2 * SEG_CAT;
  convert_kernel<<<(conv_total + 255) / 256, 256, 0, stream>>>(
      (const float4*)x, (const float4*)Wis, (const float4*)Wig, (const float4*)W_out,
      W_B, W_C, W_B_b, W_C_b,
      (u16x4_t*)xb, (u16x4_t*)wisb, (u16x4_t*)wigb, (u16x4_t*)woutb,
      (u16x4_t*)wcf, (u16x4_t*)wcb);

  // 1b. composite delta weight M = dtW @ W_dt into wcat rows 32..1567
  mcomp_kernel<<<dim3(DI / 256, DI / 16, 2), 256, 0, stream>>>(
      W_dt, dtW, W_dt_b, dtW_b, wcf, wcb);

  // 2. in-proj: [xs | silu(z)] = x @ [Wis; Wig]^T
  gemm_bt<<<dim3(3072 / 128, ML / 128, 1), 256, 0, stream>>>(
      xb, wisb, wigb, DI, xsg, ML, 3072, DM, 3072, 0, nullptr, nullptr, nullptr);

  // 3. causal conv + silu (fwd + reversed)
  conv_kernel<<<(ML * DI) / 256, 256, 0, stream>>>(
      xsg, conv_w, conv_b, conv_wb, conv_bb, xc, xcb);

  // 4. proj GEMMs: [B|C|delta_arg] = xc @ wcat^T (fp32 out), both dirs.
  //    NOTE: delta_arg bias dtb is applied inside softplus_arg? No — dtb must
  //    be added; softplus arg = delta_arg + dtb. Added in scans via... see
  //    scan kernels: softplus_f(dbase[..]) — dtb is folded into wcat? It is
  //    NOT a function of k, so it cannot be a GEMM row. It is added in the
  //    scan kernels through the dtb pointer passed below? -- handled: scans
  //    take raw arg; dtb added there? (see scan_* : they call softplus on the
  //    raw value; dtb addition is fused into mcomp? impossible.)
  gemm_bt<<<dim3(PN / 128, ML / 128, 2), 256, 0, stream>>>(
      xc, wcf, nullptr, 1 << 30, pf, ML, PN, DI, PLD, 2, xcb, wcb, pb);

  // 4b. add dtb to delta_arg columns (elementwise, tiny): fused into scans is
  //     cheaper, but keep correctness explicit this round:
  {
    // dtb[d] broadcast-add over pf/pb cols [32,1568)
    struct Local {
      static __global__ void add_bias(float* pf_, float* pb_,
                                      const float* dtb_, const float* dtb_b_) {
        int idx = blockIdx.x * 256 + threadIdx.x;     // over 2*ML*DI
        int d = idx % DI;
        int row = (idx / DI) % ML;
        int dir = idx / (ML * DI);
        float* p = dir ? pb_ : pf_;
        const float* bi = dir ? dtb_b_ : dtb_;
        p[(size_t)row * PLD + 32 + d] += bi[d];
      }
    };
    Local::add_bias<<<(2 * ML * DI) / 256, 256, 0, stream>>>(pf, pb, dtb, dtb_b);
  }

  // 5. segmented scan: summaries -> carries -> apply
  scan_sum<<<dim3(DI / 256, BB, 2 * NSEG), 256, 0, stream>>>(
      xc, xcb, pf, pb, A_log, A_log_b, sdl, bs);
  scan_carry<<<(2 * BB * DI * 16) / 256, 256, 0, stream>>>(
      A_log, A_log_b, sdl, bs);
  scan_apply<<<dim3(DI / 256, BB, 2 * NSEG), 256, 0, stream>>>(
      xc, xcb, pf, pb, A_log, A_log_b, Dp, Dp_b, bs, yf, ybr);

  // 6. gated combine + un-reverse (in place over yf)
  combine_kernel<<<(ML * DI) / 256, 256, 0, stream>>>(ybr, xsg, yf);

  // 7. out-proj: out = yf @ W_out^T, FP32 to d_out
  gemm_bt<<<dim3(DM / 128, ML / 128, 1), 256, 0, stream>>>(
      yf, woutb, nullptr, 1 << 30, d_out, ML, DM, DI, DM, 2, nullptr, nullptr, nullptr);
}

// Round 10
// 298.704 us; speedup vs baseline: 1.1328x; 1.1328x over previous
//
#include <hip/hip_runtime.h>
#include <hip/hip_bf16.h>
#include <stdint.h>

// Problem dims (fixed by the reference)
#define DM 768
#define DI 1536
#define DSTATE 16
#define RNK 48
#define BB 2
#define LL 1024
#define ML (BB * LL)  // 2048 rows (b*l flattened)

// segmented scan config
#define NSEG 32
#define SEGL (LL / NSEG)   // 32

// proj output layout: [B(16) | C(16) | delta_arg(1536)] -> N=1568, pad to 1664
#define PN 1664
#define PLD 1664

typedef unsigned short u16;
typedef __bf16 bf16x8 __attribute__((ext_vector_type(8)));
typedef float f32x4 __attribute__((ext_vector_type(4)));

struct __align__(8) u16x4_t { u16 x, y, z, w; };

__device__ __forceinline__ float b2f(u16 u) {
  union { uint32_t i; float f; } v; v.i = ((uint32_t)u) << 16; return v.f;
}
__device__ __forceinline__ u16 f2b(float f) {
  union { float f; uint32_t i; } v; v.f = f;
  uint32_t r = v.i + 0x7FFFu + ((v.i >> 16) & 1u);  // RNE
  return (u16)(r >> 16);
}
__device__ __forceinline__ float silu_f(float x) { return x / (1.f + __expf(-x)); }
// fast softplus: max(s,0) + log(1+exp(-|s|)); HW exp/log only (~1e-7 abs err)
__device__ __forceinline__ float softplus_f(float s) {
  return fmaxf(s, 0.f) + __logf(1.f + __expf(-fabsf(s)));
}
__device__ __forceinline__ u16x4_t cvt4(float4 v) {
  u16x4_t o; o.x = f2b(v.x); o.y = f2b(v.y); o.z = f2b(v.z); o.w = f2b(v.w); return o;
}

// ---------------------------------------------------------------------------
// Fused fp32->bf16 conversion of GEMM operands + proj-weight partial fill.
// cat rows (of the 1664-row B-matrix): [0..15]=W_B, [16..31]=W_C,
// [1568..1663]=0. Rows 32..1567 (composite M) are written by mcomp_kernel.
// ---------------------------------------------------------------------------
#define SEG_X    (ML * DM / 4)
#define SEG_W    (DI * DM / 4)
#define SEG_CAT  (128 * DI / 4)
__global__ __launch_bounds__(256) void convert_kernel(
    const float4* __restrict__ x, const float4* __restrict__ wis,
    const float4* __restrict__ wig, const float4* __restrict__ wout,
    const float* __restrict__ W_B, const float* __restrict__ W_C,
    const float* __restrict__ W_B_b, const float* __restrict__ W_C_b,
    u16x4_t* __restrict__ xb, u16x4_t* __restrict__ wisb,
    u16x4_t* __restrict__ wigb, u16x4_t* __restrict__ woutb,
    u16x4_t* __restrict__ wcf, u16x4_t* __restrict__ wcb)
{
  int idx = blockIdx.x * 256 + threadIdx.x;
  if (idx < SEG_X) { xb[idx] = cvt4(x[idx]); return; }
  idx -= SEG_X;
  if (idx < SEG_W) { wisb[idx] = cvt4(wis[idx]); return; }
  idx -= SEG_W;
  if (idx < SEG_W) { wigb[idx] = cvt4(wig[idx]); return; }
  idx -= SEG_W;
  if (idx < SEG_W) { woutb[idx] = cvt4(wout[idx]); return; }
  idx -= SEG_W;
  int dir = idx / SEG_CAT;
  int rem = idx % SEG_CAT;
  int row = rem / (DI / 4), k4 = rem % (DI / 4);
  const float* src = nullptr;
  if (row < 16)      src = (dir ? W_B_b : W_B) + (size_t)row * DI + k4 * 4;
  else if (row < 32) src = (dir ? W_C_b : W_C) + (size_t)(row - 16) * DI + k4 * 4;
  int prow = (row < 32) ? row : row + 1536;           // zeros land at 1568..1663
  u16x4_t o;
  if (src) o = cvt4(*(const float4*)src);
  else { o.x = 0; o.y = 0; o.z = 0; o.w = 0; }
  (dir ? wcb : wcf)[(size_t)prow * (DI / 4) + k4] = o;
}

// ---------------------------------------------------------------------------
// Composite delta weight: M[d,k] = sum_r dtW[d,r] * W_dt[r,k], bf16 into
// wcat rows 32+d.
// ---------------------------------------------------------------------------
__global__ __launch_bounds__(256) void mcomp_kernel(
    const float* __restrict__ W_dt, const float* __restrict__ dtW,
    const float* __restrict__ W_dt_b, const float* __restrict__ dtW_b,
    u16* __restrict__ wcf, u16* __restrict__ wcb)
{
  const int dir = blockIdx.z;
  const float* Wd = dir ? W_dt_b : W_dt;   // (RNK, DI)
  const float* Dw = dir ? dtW_b : dtW;     // (DI, RNK)
  u16* wcat = dir ? wcb : wcf;
  const int d0 = blockIdx.y * 16;
  const int k = blockIdx.x * 256 + threadIdx.x;

  __shared__ float dtw_sh[16][RNK];        // 3 KB
  for (int i = threadIdx.x; i < 16 * RNK; i += 256) {
    int dd = i / RNK, r = i % RNK;
    dtw_sh[dd][r] = Dw[(size_t)(d0 + dd) * RNK + r];
  }
  __syncthreads();

  float acc[16];
#pragma unroll
  for (int dd = 0; dd < 16; ++dd) acc[dd] = 0.f;
  for (int r = 0; r < RNK; ++r) {
    float wv = Wd[(size_t)r * DI + k];
#pragma unroll
    for (int dd = 0; dd < 16; ++dd) acc[dd] += dtw_sh[dd][r] * wv;
  }
#pragma unroll
  for (int dd = 0; dd < 16; ++dd)
    wcat[(size_t)(32 + d0 + dd) * DI + k] = f2b(acc[dd]);
}

// ---------------------------------------------------------------------------
// Generic bf16 GEMM: C = A (MxK) @ B^T (NxK). 128x128 tile, 4 waves,
// 16x16x32 MFMA. ROUND-9: register double-buffer pipeline — next K-tile's
// global loads issue BEFORE the MFMA block and drain at the next ds_write,
// hiding ~600cyc load latency behind compute (kernel was latency-bound:
// MfmaUtil 14%, VALUBusy 26%, Occ 14%, no wall).
// ---------------------------------------------------------------------------
__global__ __launch_bounds__(256) void gemm_bt(
    const u16* __restrict__ A, const u16* __restrict__ B0,
    const u16* __restrict__ B1, int Nsplit,
    void* __restrict__ Cout, int M, int N, int K, int ldc, int epi,
    const u16* __restrict__ A2, const u16* __restrict__ B2,
    void* __restrict__ C2)
{
  if (blockIdx.z) { A = A2; B0 = B2; Cout = C2; }
  __shared__ alignas(16) u16 As[128 * 32];
  __shared__ alignas(16) u16 Bs[128 * 32];
  const int tid = threadIdx.x;
  const int wave = tid >> 6, lane = tid & 63;
  const int bm = blockIdx.y * 128;
  const int bn = blockIdx.x * 128;

  const u16* Bmat = B0;
  int ncol0 = bn;
  int epi_l = epi;
  if (B1 != nullptr && bn >= Nsplit) { Bmat = B1; ncol0 = bn - Nsplit; epi_l = 1; }

  const int c0 = tid, c1 = tid + 256;
  const u16* gA0 = A + (size_t)(bm + (c0 >> 2)) * K + (c0 & 3) * 8;
  const u16* gA1 = A + (size_t)(bm + (c1 >> 2)) * K + (c1 & 3) * 8;
  const u16* gB0 = Bmat + (size_t)(ncol0 + (c0 >> 2)) * K + (c0 & 3) * 8;
  const u16* gB1 = Bmat + (size_t)(ncol0 + (c1 >> 2)) * K + (c1 & 3) * 8;
  uint4* lA0 = (uint4*)&As[c0 * 8]; uint4* lA1 = (uint4*)&As[c1 * 8];
  uint4* lB0 = (uint4*)&Bs[c0 * 8]; uint4* lB1 = (uint4*)&Bs[c1 * 8];

  const int wm = (wave & 1) * 64, wn = (wave >> 1) * 64;
  const int rl = lane & 15, q = lane >> 4;

  f32x4 acc[4][4];
#pragma unroll
  for (int i = 0; i < 4; ++i)
#pragma unroll
    for (int j = 0; j < 4; ++j) acc[i][j] = (f32x4){0.f, 0.f, 0.f, 0.f};

  const bf16x8* AsV = (const bf16x8*)As;
  const bf16x8* BsV = (const bf16x8*)Bs;

  // pipeline prologue: tile 0 into registers
  uint4 ra0 = *(const uint4*)(gA0);
  uint4 ra1 = *(const uint4*)(gA1);
  uint4 rb0 = *(const uint4*)(gB0);
  uint4 rb1 = *(const uint4*)(gB1);

  for (int k0 = 0; k0 < K; k0 += 32) {
    *lA0 = ra0; *lA1 = ra1; *lB0 = rb0; *lB1 = rb1;
    __syncthreads();
    if (k0 + 32 < K) {               // issue next tile loads; waited at next ds_write
      ra0 = *(const uint4*)(gA0 + k0 + 32);
      ra1 = *(const uint4*)(gA1 + k0 + 32);
      rb0 = *(const uint4*)(gB0 + k0 + 32);
      rb1 = *(const uint4*)(gB1 + k0 + 32);
    }
    bf16x8 af[4], bfv[4];
#pragma unroll
    for (int s = 0; s < 4; ++s) {
      af[s]  = AsV[(wm + s * 16 + rl) * 4 + q];
      bfv[s] = BsV[(wn + s * 16 + rl) * 4 + q];
    }
#pragma unroll
    for (int i = 0; i < 4; ++i)
#pragma unroll
      for (int j = 0; j < 4; ++j)
        acc[i][j] = __builtin_amdgcn_mfma_f32_16x16x32_bf16(af[i], bfv[j], acc[i][j], 0, 0, 0);
    __syncthreads();
  }

#pragma unroll
  for (int i = 0; i < 4; ++i) {
#pragma unroll
    for (int j = 0; j < 4; ++j) {
#pragma unroll
      for (int r = 0; r < 4; ++r) {
        int row = bm + wm + i * 16 + q * 4 + r;
        int col = bn + wn + j * 16 + rl;
        float v = acc[i][j][r];
        if (epi_l == 1) v = silu_f(v);
        if (epi == 2) ((float*)Cout)[(size_t)row * ldc + col] = v;
        else          ((u16*)Cout)[(size_t)row * ldc + col] = f2b(v);
      }
    }
  }
}

// ---------------------------------------------------------------------------
// Causal depthwise conv (K=4, fp32 weights) + SiLU, fwd + reversed.
// ---------------------------------------------------------------------------
__global__ void conv_kernel(
    const u16* __restrict__ xsg,
    const float* __restrict__ cw, const float* __restrict__ cb,
    const float* __restrict__ cwb, const float* __restrict__ cbb,
    u16* __restrict__ xc, u16* __restrict__ xcb)
{
  int idx = blockIdx.x * 256 + threadIdx.x;      // over ML*DI
  int d = idx % DI;
  int row = idx / DI;
  int l = row % LL, b = row / LL;
  const u16* base = xsg + (size_t)b * LL * 3072 + d;

  float4 wf = *(const float4*)(cw + d * 4);
  float4 wb = *(const float4*)(cwb + d * 4);
  float wfk[4] = {wf.x, wf.y, wf.z, wf.w};
  float wbk[4] = {wb.x, wb.y, wb.z, wb.w};

  float accf = cb[d];
  float accb = cbb[d];
#pragma unroll
  for (int k = 0; k < 4; ++k) {
    int ls = l - 3 + k;
    if (ls >= 0) {
      accf += wfk[k] * b2f(base[(size_t)ls * 3072]);
      accb += wbk[k] * b2f(base[(size_t)(LL - 1 - ls) * 3072]);
    }
  }
  xc[idx]  = f2b(silu_f(accf));
  xcb[idx] = f2b(silu_f(accb));
}

// ---------------------------------------------------------------------------
// Segmented scan, phase A. delta = softplus(delta_arg + dtb[d]) — dtb folded
// here (round 9: add_bias kernel deleted; same fp32 op order => bit-identical).
// ---------------------------------------------------------------------------
__global__ __launch_bounds__(256) void scan_sum(
    const u16* __restrict__ xcf, const u16* __restrict__ xcb,
    const float* __restrict__ pf, const float* __restrict__ pb,
    const float* __restrict__ A_log, const float* __restrict__ A_log_b,
    const float* __restrict__ dtb, const float* __restrict__ dtb_b,
    float* __restrict__ sdl, float* __restrict__ bs)
{
  const int dir = blockIdx.z / NSEG, seg = blockIdx.z % NSEG;
  const u16* xc = dir ? xcb : xcf;
  const float* proj = dir ? pb : pf;
  const float* Al = dir ? A_log_b : A_log;
  const float* bias = dir ? dtb_b : dtb;
  const int b = blockIdx.y;
  const int d = blockIdx.x * 256 + threadIdx.x;
  const int l0 = seg * SEGL;

  __shared__ float Bsh[SEGL][16];
  for (int i = threadIdx.x; i < SEGL * 16; i += 256) {
    int l = i >> 4, n = i & 15;
    Bsh[l][n] = proj[((size_t)b * LL + l0 + l) * PLD + n];
  }
  __syncthreads();

  float An[16];
#pragma unroll
  for (int n = 0; n < 16; ++n) An[n] = -__expf(Al[d * 16 + n]);
  const float bv = bias[d];

  float h[16];
#pragma unroll
  for (int n = 0; n < 16; ++n) h[n] = 0.f;
  float S = 0.f;

  const float* dbase = proj + ((size_t)b * LL + l0) * PLD + 32 + d;
  const u16* xbase = xc + ((size_t)b * LL + l0) * DI + d;

  for (int g = 0; g < SEGL; g += 4) {
    float dl4[4], dx4[4];
#pragma unroll
    for (int j = 0; j < 4; ++j) {
      float dv = softplus_f(dbase[(size_t)(g + j) * PLD] + bv);
      float xv = b2f(xbase[(size_t)(g + j) * DI]);
      dl4[j] = dv; dx4[j] = dv * xv;
    }
#pragma unroll
    for (int j = 0; j < 4; ++j) {
      S += dl4[j];
#pragma unroll
      for (int n = 0; n < 16; ++n)
        h[n] = __expf(dl4[j] * An[n]) * h[n] + dx4[j] * Bsh[g + j][n];
    }
  }

  size_t base = (((size_t)dir * BB + b) * NSEG + seg) * DI + d;
  sdl[base] = S;
#pragma unroll
  for (int n = 0; n < 16; ++n) bs[base * 16 + n] = h[n];
}

// ---------------------------------------------------------------------------
// Phase B: compose segment summaries into carry-ins (bs overwritten in place).
// ---------------------------------------------------------------------------
__global__ __launch_bounds__(256) void scan_carry(
    const float* __restrict__ A_log, const float* __restrict__ A_log_b,
    const float* __restrict__ sdl, float* __restrict__ bs)
{
  int idx = blockIdx.x * 256 + threadIdx.x;   // over 2*BB*DI*16
  int n = idx & 15;
  int t = idx >> 4;
  int d = t % DI;
  int b = (t / DI) % BB;
  int dir = t / (DI * BB);
  const float* Al = dir ? A_log_b : A_log;
  float An = -__expf(Al[d * 16 + n]);
  float h = 0.f;
  for (int s = 0; s < NSEG; ++s) {
    size_t base = (((size_t)dir * BB + b) * NSEG + s) * DI + d;
    float S = sdl[base];
    float bv = bs[base * 16 + n];
    bs[base * 16 + n] = h;
    h = __expf(S * An) * h + bv;
  }
}

// ---------------------------------------------------------------------------
// Phase C: redo recurrence from carry-in, compute y. dtb folded (see scan_sum).
// ---------------------------------------------------------------------------
__global__ __launch_bounds__(256) void scan_apply(
    const u16* __restrict__ xcf, const u16* __restrict__ xcb,
    const float* __restrict__ pf, const float* __restrict__ pb,
    const float* __restrict__ A_log, const float* __restrict__ A_log_b,
    const float* __restrict__ Dp, const float* __restrict__ Dp_b,
    const float* __restrict__ dtb, const float* __restrict__ dtb_b,
    const float* __restrict__ bs,
    u16* __restrict__ y_f, u16* __restrict__ y_b)
{
  const int dir = blockIdx.z / NSEG, seg = blockIdx.z % NSEG;
  const u16* xc = dir ? xcb : xcf;
  const float* proj = dir ? pb : pf;
  const float* Al = dir ? A_log_b : A_log;
  const float* Dpp = dir ? Dp_b : Dp;
  const float* bias = dir ? dtb_b : dtb;
  u16* y = dir ? y_b : y_f;
  const int b = blockIdx.y;
  const int d = blockIdx.x * 256 + threadIdx.x;
  const int l0 = seg * SEGL;

  __shared__ float BCsh[SEGL][32];            // [l][0:16)=B, [16:32)=C
  for (int i = threadIdx.x; i < SEGL * 32; i += 256) {
    int l = i >> 5, j = i & 31;
    BCsh[l][j] = proj[((size_t)b * LL + l0 + l) * PLD + j];
  }
  __syncthreads();

  float An[16];
#pragma unroll
  for (int n = 0; n < 16; ++n) An[n] = -__expf(Al[d * 16 + n]);
  const float Dv = Dpp[d];
  const float bv = bias[d];

  float h[16];
  size_t cbase = (((size_t)dir * BB + b) * NSEG + seg) * DI + d;
#pragma unroll
  for (int n = 0; n < 16; ++n) h[n] = bs[cbase * 16 + n];

  const float* dbase = proj + ((size_t)b * LL + l0) * PLD + 32 + d;
  const u16* xbase = xc + ((size_t)b * LL + l0) * DI + d;
  u16* ybase = y + ((size_t)b * LL + l0) * DI + d;

  for (int g = 0; g < SEGL; g += 4) {
    float dl4[4], xv4[4];
#pragma unroll
    for (int j = 0; j < 4; ++j) {
      dl4[j] = softplus_f(dbase[(size_t)(g + j) * PLD] + bv);
      xv4[j] = b2f(xbase[(size_t)(g + j) * DI]);
    }
#pragma unroll
    for (int j = 0; j < 4; ++j) {
      float dx = dl4[j] * xv4[j];
      float yv = 0.f;
#pragma unroll
      for (int n = 0; n < 16; ++n) {
        h[n] = __expf(dl4[j] * An[n]) * h[n] + dx * BCsh[g + j][n];
        yv += h[n] * BCsh[g + j][16 + n];
      }
      ybase[(size_t)(g + j) * DI] = f2b(yv + Dv * xv4[j]);
    }
  }
}

// ---------------------------------------------------------------------------
// y_comb[l] = 0.5 * silu(z[l]) * (y_f[l] + y_b_rev[L-1-l]); in-place over yf.
// ---------------------------------------------------------------------------
__global__ void combine_kernel(
    const u16* __restrict__ ybr, const u16* __restrict__ xsg, u16* yf)
{
  int idx = blockIdx.x * 256 + threadIdx.x;      // over ML*DI
  int d = idx % DI;
  int row = idx / DI;
  int l = row % LL, b = row / LL;
  float g = b2f(xsg[(size_t)row * 3072 + DI + d]);
  float vb = b2f(ybr[((size_t)b * LL + (LL - 1 - l)) * DI + d]);
  float v = 0.5f * (b2f(yf[idx]) + vb) * g;
  yf[idx] = f2b(v);
}

// ---------------------------------------------------------------------------
extern "C" void kernel_launch(void* const* d_in, const int* in_sizes, int n_in,
                              void* d_out, int out_size, void* d_ws, size_t ws_size,
                              hipStream_t stream)
{
  const float* x       = (const float*)d_in[0];
  const float* Wis     = (const float*)d_in[1];
  const float* Wig     = (const float*)d_in[2];
  const float* conv_w  = (const float*)d_in[3];
  const float* conv_b  = (const float*)d_in[4];
  const float* conv_wb = (const float*)d_in[5];
  const float* conv_bb = (const float*)d_in[6];
  const float* W_dt    = (const float*)d_in[7];
  const float* W_B     = (const float*)d_in[8];
  const float* W_C     = (const float*)d_in[9];
  const float* dtW     = (const float*)d_in[10];
  const float* dtb     = (const float*)d_in[11];
  const float* A_log   = (const float*)d_in[12];
  const float* Dp      = (const float*)d_in[13];
  const float* W_dt_b  = (const float*)d_in[14];
  const float* W_B_b   = (const float*)d_in[15];
  const float* W_C_b   = (const float*)d_in[16];
  const float* dtW_b   = (const float*)d_in[17];
  const float* dtb_b   = (const float*)d_in[18];
  const float* A_log_b = (const float*)d_in[19];
  const float* Dp_b    = (const float*)d_in[20];
  const float* W_out   = (const float*)d_in[21];

  char* ws = (char*)d_ws;
  size_t off = 0;
  auto alloc = [&](size_t bytes) -> char* {
    char* p = ws + off; off += (bytes + 255) & ~(size_t)255; return p;
  };
  u16*   xb    = (u16*)alloc((size_t)ML * DM * 2);
  u16*   wisb  = (u16*)alloc((size_t)DI * DM * 2);
  u16*   wigb  = (u16*)alloc((size_t)DI * DM * 2);
  u16*   woutb = (u16*)alloc((size_t)DM * DI * 2);
  u16*   xsg = (u16*)alloc((size_t)ML * 3072 * 2);     // [xs | silu(z)]
  u16*   xc  = (u16*)alloc((size_t)ML * DI * 2);
  u16*   xcb = (u16*)alloc((size_t)ML * DI * 2);       // reversed space
  u16*   wcf = (u16*)alloc((size_t)PN * DI * 2);       // 5.1 MB (B|C|M|0)
  u16*   wcb = (u16*)alloc((size_t)PN * DI * 2);
  float* pf  = (float*)alloc((size_t)ML * PLD * 4);    // 13.6 MB
  float* pb  = (float*)alloc((size_t)ML * PLD * 4);
  u16*   yf  = (u16*)alloc((size_t)ML * DI * 2);       // later holds combined y
  u16*   ybr = (u16*)alloc((size_t)ML * DI * 2);       // reversed space
  float* sdl = (float*)alloc((size_t)2 * BB * NSEG * DI * 4);
  float* bs  = (float*)alloc((size_t)2 * BB * NSEG * DI * 16 * 4);
  // total ~96 MB

  // 1. fp32->bf16 conversion + proj B/C/zero rows
  const int conv_total = SEG_X + 3 * SEG_W + 2 * SEG_CAT;
  convert_kernel<<<(conv_total + 255) / 256, 256, 0, stream>>>(
      (const float4*)x, (const float4*)Wis, (const float4*)Wig, (const float4*)W_out,
      W_B, W_C, W_B_b, W_C_b,
      (u16x4_t*)xb, (u16x4_t*)wisb, (u16x4_t*)wigb, (u16x4_t*)woutb,
      (u16x4_t*)wcf, (u16x4_t*)wcb);

  // 1b. composite delta weight M = dtW @ W_dt into wcat rows 32..1567
  mcomp_kernel<<<dim3(DI / 256, DI / 16, 2), 256, 0, stream>>>(
      W_dt, dtW, W_dt_b, dtW_b, wcf, wcb);

  // 2. in-proj: [xs | silu(z)] = x @ [Wis; Wig]^T
  gemm_bt<<<dim3(3072 / 128, ML / 128, 1), 256, 0, stream>>>(
      xb, wisb, wigb, DI, xsg, ML, 3072, DM, 3072, 0, nullptr, nullptr, nullptr);

  // 3. causal conv + silu (fwd + reversed)
  conv_kernel<<<(ML * DI) / 256, 256, 0, stream>>>(
      xsg, conv_w, conv_b, conv_wb, conv_bb, xc, xcb);

  // 4. proj GEMMs: [B|C|delta_arg] = xc @ wcat^T (fp32 out), both dirs.
  //    dtb is added inside the scan kernels (softplus(arg + dtb[d])).
  gemm_bt<<<dim3(PN / 128, ML / 128, 2), 256, 0, stream>>>(
      xc, wcf, nullptr, 1 << 30, pf, ML, PN, DI, PLD, 2, xcb, wcb, pb);

  // 5. segmented scan: summaries -> carries -> apply
  scan_sum<<<dim3(DI / 256, BB, 2 * NSEG), 256, 0, stream>>>(
      xc, xcb, pf, pb, A_log, A_log_b, dtb, dtb_b, sdl, bs);
  scan_carry<<<(2 * BB * DI * 16) / 256, 256, 0, stream>>>(
      A_log, A_log_b, sdl, bs);
  scan_apply<<<dim3(DI / 256, BB, 2 * NSEG), 256, 0, stream>>>(
      xc, xcb, pf, pb, A_log, A_log_b, Dp, Dp_b, dtb, dtb_b, bs, yf, ybr);

  // 6. gated combine + un-reverse (in place over yf)
  combine_kernel<<<(ML * DI) / 256, 256, 0, stream>>>(ybr, xsg, yf);

  // 7. out-proj: out = yf @ W_out^T, FP32 to d_out
  gemm_bt<<<dim3(DM / 128, ML / 128, 1), 256, 0, stream>>>(
      yf, woutb, nullptr, 1 << 30, d_out, ML, DM, DI, DM, 2, nullptr, nullptr, nullptr);
}

// Round 11
// 296.549 us; speedup vs baseline: 1.1410x; 1.0073x over previous
//
#include <hip/hip_runtime.h>
#include <hip/hip_bf16.h>
#include <stdint.h>

// Problem dims (fixed by the reference)
#define DM 768
#define DI 1536
#define DSTATE 16
#define RNK 48
#define BB 2
#define LL 1024
#define ML (BB * LL)  // 2048 rows (b*l flattened)

// segmented scan config
#define NSEG 32
#define SEGL (LL / NSEG)   // 32

typedef unsigned short u16;
typedef __bf16 bf16x8 __attribute__((ext_vector_type(8)));
typedef float f32x4 __attribute__((ext_vector_type(4)));

struct __align__(8) u16x4_t { u16 x, y, z, w; };

__device__ __forceinline__ float b2f(u16 u) {
  union { uint32_t i; float f; } v; v.i = ((uint32_t)u) << 16; return v.f;
}
__device__ __forceinline__ u16 f2b(float f) {
  union { float f; uint32_t i; } v; v.f = f;
  uint32_t r = v.i + 0x7FFFu + ((v.i >> 16) & 1u);  // RNE
  return (u16)(r >> 16);
}
__device__ __forceinline__ float silu_f(float x) { return x / (1.f + __expf(-x)); }
// fast softplus: max(s,0) + log(1+exp(-|s|)); HW exp/log only (~1e-7 abs err)
__device__ __forceinline__ float softplus_f(float s) {
  return fmaxf(s, 0.f) + __logf(1.f + __expf(-fabsf(s)));
}
__device__ __forceinline__ u16x4_t cvt4(float4 v) {
  u16x4_t o; o.x = f2b(v.x); o.y = f2b(v.y); o.z = f2b(v.z); o.w = f2b(v.w); return o;
}

// ---------------------------------------------------------------------------
// Fused fp32->bf16 conversion of GEMM operands + small-weight packing.
// Segments (float4 units): x | Wis | Wig | Wout | wcat(2 dirs) | dtWb(2 dirs)
// wcat (128x1536): rows 0..15=W_B, 16..31=W_C, 32..79=W_dt, 80..127=0
// dtWb (1536x64):  cols 0..47=dtW row, 48..63=0  (K-padded for MFMA)
// ---------------------------------------------------------------------------
#define SEG_X    (ML * DM / 4)
#define SEG_W    (DI * DM / 4)
#define SEG_CAT  (128 * DI / 4)     // 49152 per direction
#define SEG_DTW  (DI * 64 / 4)      // 24576 per direction
__global__ __launch_bounds__(256) void convert_kernel(
    const float4* __restrict__ x, const float4* __restrict__ wis,
    const float4* __restrict__ wig, const float4* __restrict__ wout,
    const float* __restrict__ W_B, const float* __restrict__ W_C,
    const float* __restrict__ W_dt,
    const float* __restrict__ W_B_b, const float* __restrict__ W_C_b,
    const float* __restrict__ W_dt_b,
    const float* __restrict__ dtW, const float* __restrict__ dtW_b,
    u16x4_t* __restrict__ xb, u16x4_t* __restrict__ wisb,
    u16x4_t* __restrict__ wigb, u16x4_t* __restrict__ woutb,
    u16x4_t* __restrict__ wcf, u16x4_t* __restrict__ wcb,
    u16x4_t* __restrict__ dtwf, u16x4_t* __restrict__ dtwb)
{
  int idx = blockIdx.x * 256 + threadIdx.x;
  if (idx < SEG_X) { xb[idx] = cvt4(x[idx]); return; }
  idx -= SEG_X;
  if (idx < SEG_W) { wisb[idx] = cvt4(wis[idx]); return; }
  idx -= SEG_W;
  if (idx < SEG_W) { wigb[idx] = cvt4(wig[idx]); return; }
  idx -= SEG_W;
  if (idx < SEG_W) { woutb[idx] = cvt4(wout[idx]); return; }
  idx -= SEG_W;
  if (idx < 2 * SEG_CAT) {
    int dir = idx / SEG_CAT;
    int rem = idx % SEG_CAT;
    int row = rem / (DI / 4), k4 = rem % (DI / 4);
    const float* src = nullptr;
    if (row < 16)      src = (dir ? W_B_b  : W_B)  + (size_t)row * DI + k4 * 4;
    else if (row < 32) src = (dir ? W_C_b  : W_C)  + (size_t)(row - 16) * DI + k4 * 4;
    else if (row < 80) src = (dir ? W_dt_b : W_dt) + (size_t)(row - 32) * DI + k4 * 4;
    u16x4_t o;
    if (src) o = cvt4(*(const float4*)src);
    else { o.x = 0; o.y = 0; o.z = 0; o.w = 0; }
    (dir ? wcb : wcf)[rem] = o;
    return;
  }
  idx -= 2 * SEG_CAT;
  // dtWb segment
  int dir = idx / SEG_DTW;
  int rem = idx % SEG_DTW;
  int d = rem / 16, r4 = rem % 16;          // 16 float4 per 64-col row
  const float* Dw = dir ? dtW_b : dtW;
  u16x4_t o;
  if (r4 < 12) o = cvt4(*(const float4*)(Dw + (size_t)d * RNK + r4 * 4));
  else { o.x = 0; o.y = 0; o.z = 0; o.w = 0; }
  (dir ? dtwb : dtwf)[rem] = o;
}

// ---------------------------------------------------------------------------
// Generic bf16 GEMM: C = A (MxK) @ B^T (NxK). 128x128 tile, 4 waves,
// 16x16x32 MFMA, reg double-buffer pipeline (round 9).
// epi: 0 bf16 store (dual-B silu via B1/Nsplit) | 2 fp32 store |
//      5 proj: col<32 fp32->Cout(ld 32), 32<=col<96 bf16->Caux(ld 64), else skip
//      6 delta: fp32 softplus(acc + ebias[col]) -> Cout (ld ldc)
// blockIdx.z==1 switches to (A2,B2,C2,Caux2,ebias2).
// ---------------------------------------------------------------------------
__global__ __launch_bounds__(256) void gemm_bt(
    const u16* __restrict__ A, const u16* __restrict__ B0,
    const u16* __restrict__ B1, int Nsplit,
    void* __restrict__ Cout, int M, int N, int K, int ldc, int epi,
    const u16* __restrict__ A2, const u16* __restrict__ B2,
    void* __restrict__ C2,
    u16* __restrict__ Caux, u16* __restrict__ Caux2,
    const float* __restrict__ ebias, const float* __restrict__ ebias2)
{
  if (blockIdx.z) { A = A2; B0 = B2; Cout = C2; Caux = Caux2; ebias = ebias2; }
  __shared__ alignas(16) u16 As[128 * 32];
  __shared__ alignas(16) u16 Bs[128 * 32];
  const int tid = threadIdx.x;
  const int wave = tid >> 6, lane = tid & 63;
  const int bm = blockIdx.y * 128;
  const int bn = blockIdx.x * 128;

  const u16* Bmat = B0;
  int ncol0 = bn;
  int epi_l = epi;
  if (B1 != nullptr && bn >= Nsplit) { Bmat = B1; ncol0 = bn - Nsplit; epi_l = 1; }

  const int c0 = tid, c1 = tid + 256;
  const u16* gA0 = A + (size_t)(bm + (c0 >> 2)) * K + (c0 & 3) * 8;
  const u16* gA1 = A + (size_t)(bm + (c1 >> 2)) * K + (c1 & 3) * 8;
  const u16* gB0 = Bmat + (size_t)(ncol0 + (c0 >> 2)) * K + (c0 & 3) * 8;
  const u16* gB1 = Bmat + (size_t)(ncol0 + (c1 >> 2)) * K + (c1 & 3) * 8;
  uint4* lA0 = (uint4*)&As[c0 * 8]; uint4* lA1 = (uint4*)&As[c1 * 8];
  uint4* lB0 = (uint4*)&Bs[c0 * 8]; uint4* lB1 = (uint4*)&Bs[c1 * 8];

  const int wm = (wave & 1) * 64, wn = (wave >> 1) * 64;
  const int rl = lane & 15, q = lane >> 4;

  f32x4 acc[4][4];
#pragma unroll
  for (int i = 0; i < 4; ++i)
#pragma unroll
    for (int j = 0; j < 4; ++j) acc[i][j] = (f32x4){0.f, 0.f, 0.f, 0.f};

  const bf16x8* AsV = (const bf16x8*)As;
  const bf16x8* BsV = (const bf16x8*)Bs;

  // pipeline prologue: tile 0 into registers
  uint4 ra0 = *(const uint4*)(gA0);
  uint4 ra1 = *(const uint4*)(gA1);
  uint4 rb0 = *(const uint4*)(gB0);
  uint4 rb1 = *(const uint4*)(gB1);

  for (int k0 = 0; k0 < K; k0 += 32) {
    *lA0 = ra0; *lA1 = ra1; *lB0 = rb0; *lB1 = rb1;
    __syncthreads();
    if (k0 + 32 < K) {               // issue next tile loads; waited at next ds_write
      ra0 = *(const uint4*)(gA0 + k0 + 32);
      ra1 = *(const uint4*)(gA1 + k0 + 32);
      rb0 = *(const uint4*)(gB0 + k0 + 32);
      rb1 = *(const uint4*)(gB1 + k0 + 32);
    }
    bf16x8 af[4], bfv[4];
#pragma unroll
    for (int s = 0; s < 4; ++s) {
      af[s]  = AsV[(wm + s * 16 + rl) * 4 + q];
      bfv[s] = BsV[(wn + s * 16 + rl) * 4 + q];
    }
#pragma unroll
    for (int i = 0; i < 4; ++i)
#pragma unroll
      for (int j = 0; j < 4; ++j)
        acc[i][j] = __builtin_amdgcn_mfma_f32_16x16x32_bf16(af[i], bfv[j], acc[i][j], 0, 0, 0);
    __syncthreads();
  }

  // epilogue: C/D layout col=lane&15, row=(lane>>4)*4+reg
#pragma unroll
  for (int i = 0; i < 4; ++i) {
#pragma unroll
    for (int j = 0; j < 4; ++j) {
#pragma unroll
      for (int r = 0; r < 4; ++r) {
        int row = bm + wm + i * 16 + q * 4 + r;
        int col = bn + wn + j * 16 + rl;
        float v = acc[i][j][r];
        if (epi_l == 1) v = silu_f(v);
        if (epi == 5) {
          if (col < 32)      ((float*)Cout)[(size_t)row * 32 + col] = v;
          else if (col < 96) Caux[(size_t)row * 64 + (col - 32)] = f2b(v);
        } else if (epi == 6) {
          ((float*)Cout)[(size_t)row * ldc + col] = softplus_f(v + ebias[col]);
        } else if (epi == 2) {
          ((float*)Cout)[(size_t)row * ldc + col] = v;
        } else {
          ((u16*)Cout)[(size_t)row * ldc + col] = f2b(v);
        }
      }
    }
  }
}

// ---------------------------------------------------------------------------
// Causal depthwise conv (K=4, fp32 weights) + SiLU, fwd + reversed.
// ---------------------------------------------------------------------------
__global__ void conv_kernel(
    const u16* __restrict__ xsg,
    const float* __restrict__ cw, const float* __restrict__ cb,
    const float* __restrict__ cwb, const float* __restrict__ cbb,
    u16* __restrict__ xc, u16* __restrict__ xcb)
{
  int idx = blockIdx.x * 256 + threadIdx.x;      // over ML*DI
  int d = idx % DI;
  int row = idx / DI;
  int l = row % LL, b = row / LL;
  const u16* base = xsg + (size_t)b * LL * 3072 + d;

  float4 wf = *(const float4*)(cw + d * 4);
  float4 wb = *(const float4*)(cwb + d * 4);
  float wfk[4] = {wf.x, wf.y, wf.z, wf.w};
  float wbk[4] = {wb.x, wb.y, wb.z, wb.w};

  float accf = cb[d];
  float accb = cbb[d];
#pragma unroll
  for (int k = 0; k < 4; ++k) {
    int ls = l - 3 + k;
    if (ls >= 0) {
      accf += wfk[k] * b2f(base[(size_t)ls * 3072]);
      accb += wbk[k] * b2f(base[(size_t)(LL - 1 - ls) * 3072]);
    }
  }
  xc[idx]  = f2b(silu_f(accf));
  xcb[idx] = f2b(silu_f(accb));
}

// ---------------------------------------------------------------------------
// Segmented scan, phase A: per (dir,b,seg,d) compute Sdelta and local
// end-state h_local[16] (h_in=0). delta precomputed (fp32, softplus applied
// in delta-GEMM epilogue). B from proj (ld 32, cols 0..15).
// ---------------------------------------------------------------------------
__global__ __launch_bounds__(256) void scan_sum(
    const float* __restrict__ df, const float* __restrict__ db,
    const u16* __restrict__ xcf, const u16* __restrict__ xcb,
    const float* __restrict__ pf, const float* __restrict__ pb,
    const float* __restrict__ A_log, const float* __restrict__ A_log_b,
    float* __restrict__ sdl, float* __restrict__ bs)
{
  const int dir = blockIdx.z / NSEG, seg = blockIdx.z % NSEG;
  const float* delta = dir ? db : df;
  const u16* xc = dir ? xcb : xcf;
  const float* proj = dir ? pb : pf;
  const float* Al = dir ? A_log_b : A_log;
  const int b = blockIdx.y;
  const int d = blockIdx.x * 256 + threadIdx.x;
  const int l0 = seg * SEGL;

  __shared__ float Bsh[SEGL][16];
  for (int i = threadIdx.x; i < SEGL * 16; i += 256) {
    int l = i >> 4, n = i & 15;
    Bsh[l][n] = proj[((size_t)b * LL + l0 + l) * 32 + n];
  }
  __syncthreads();

  float An[16];
#pragma unroll
  for (int n = 0; n < 16; ++n) An[n] = -__expf(Al[d * 16 + n]);

  float h[16];
#pragma unroll
  for (int n = 0; n < 16; ++n) h[n] = 0.f;
  float S = 0.f;

  const float* dbase = delta + ((size_t)b * LL + l0) * DI + d;
  const u16* xbase = xc + ((size_t)b * LL + l0) * DI + d;

  for (int g = 0; g < SEGL; g += 4) {
    float dl4[4], dx4[4];
#pragma unroll
    for (int j = 0; j < 4; ++j) {
      float dv = dbase[(size_t)(g + j) * DI];
      float xv = b2f(xbase[(size_t)(g + j) * DI]);
      dl4[j] = dv; dx4[j] = dv * xv;
    }
#pragma unroll
    for (int j = 0; j < 4; ++j) {
      S += dl4[j];
#pragma unroll
      for (int n = 0; n < 16; ++n)
        h[n] = __expf(dl4[j] * An[n]) * h[n] + dx4[j] * Bsh[g + j][n];
    }
  }

  size_t base = (((size_t)dir * BB + b) * NSEG + seg) * DI + d;
  sdl[base] = S;
#pragma unroll
  for (int n = 0; n < 16; ++n) bs[base * 16 + n] = h[n];
}

// ---------------------------------------------------------------------------
// Phase B: compose segment summaries into carry-ins (bs overwritten in place).
// ---------------------------------------------------------------------------
__global__ __launch_bounds__(256) void scan_carry(
    const float* __restrict__ A_log, const float* __restrict__ A_log_b,
    const float* __restrict__ sdl, float* __restrict__ bs)
{
  int idx = blockIdx.x * 256 + threadIdx.x;   // over 2*BB*DI*16
  int n = idx & 15;
  int t = idx >> 4;
  int d = t % DI;
  int b = (t / DI) % BB;
  int dir = t / (DI * BB);
  const float* Al = dir ? A_log_b : A_log;
  float An = -__expf(Al[d * 16 + n]);
  float h = 0.f;
  for (int s = 0; s < NSEG; ++s) {
    size_t base = (((size_t)dir * BB + b) * NSEG + s) * DI + d;
    float S = sdl[base];
    float bv = bs[base * 16 + n];
    bs[base * 16 + n] = h;
    h = __expf(S * An) * h + bv;
  }
}

// ---------------------------------------------------------------------------
// Phase C: redo recurrence from carry-in, compute y. B/C from proj ld 32.
// ---------------------------------------------------------------------------
__global__ __launch_bounds__(256) void scan_apply(
    const float* __restrict__ df, const float* __restrict__ db,
    const u16* __restrict__ xcf, const u16* __restrict__ xcb,
    const float* __restrict__ pf, const float* __restrict__ pb,
    const float* __restrict__ A_log, const float* __restrict__ A_log_b,
    const float* __restrict__ Dp, const float* __restrict__ Dp_b,
    const float* __restrict__ bs,
    u16* __restrict__ y_f, u16* __restrict__ y_b)
{
  const int dir = blockIdx.z / NSEG, seg = blockIdx.z % NSEG;
  const float* delta = dir ? db : df;
  const u16* xc = dir ? xcb : xcf;
  const float* proj = dir ? pb : pf;
  const float* Al = dir ? A_log_b : A_log;
  const float* Dpp = dir ? Dp_b : Dp;
  u16* y = dir ? y_b : y_f;
  const int b = blockIdx.y;
  const int d = blockIdx.x * 256 + threadIdx.x;
  const int l0 = seg * SEGL;

  __shared__ float BCsh[SEGL][32];            // [l][0:16)=B, [16:32)=C
  for (int i = threadIdx.x; i < SEGL * 32; i += 256) {
    int l = i >> 5, j = i & 31;
    BCsh[l][j] = proj[((size_t)b * LL + l0 + l) * 32 + j];
  }
  __syncthreads();

  float An[16];
#pragma unroll
  for (int n = 0; n < 16; ++n) An[n] = -__expf(Al[d * 16 + n]);
  const float Dv = Dpp[d];

  float h[16];
  size_t cbase = (((size_t)dir * BB + b) * NSEG + seg) * DI + d;
#pragma unroll
  for (int n = 0; n < 16; ++n) h[n] = bs[cbase * 16 + n];

  const float* dbase = delta + ((size_t)b * LL + l0) * DI + d;
  const u16* xbase = xc + ((size_t)b * LL + l0) * DI + d;
  u16* ybase = y + ((size_t)b * LL + l0) * DI + d;

  for (int g = 0; g < SEGL; g += 4) {
    float dl4[4], xv4[4];
#pragma unroll
    for (int j = 0; j < 4; ++j) {
      dl4[j] = dbase[(size_t)(g + j) * DI];
      xv4[j] = b2f(xbase[(size_t)(g + j) * DI]);
    }
#pragma unroll
    for (int j = 0; j < 4; ++j) {
      float dx = dl4[j] * xv4[j];
      float yv = 0.f;
#pragma unroll
      for (int n = 0; n < 16; ++n) {
        h[n] = __expf(dl4[j] * An[n]) * h[n] + dx * BCsh[g + j][n];
        yv += h[n] * BCsh[g + j][16 + n];
      }
      ybase[(size_t)(g + j) * DI] = f2b(yv + Dv * xv4[j]);
    }
  }
}

// ---------------------------------------------------------------------------
// y_comb[l] = 0.5 * silu(z[l]) * (y_f[l] + y_b_rev[L-1-l]); in-place over yf.
// ---------------------------------------------------------------------------
__global__ void combine_kernel(
    const u16* __restrict__ ybr, const u16* __restrict__ xsg, u16* yf)
{
  int idx = blockIdx.x * 256 + threadIdx.x;      // over ML*DI
  int d = idx % DI;
  int row = idx / DI;
  int l = row % LL, b = row / LL;
  float g = b2f(xsg[(size_t)row * 3072 + DI + d]);
  float vb = b2f(ybr[((size_t)b * LL + (LL - 1 - l)) * DI + d]);
  float v = 0.5f * (b2f(yf[idx]) + vb) * g;
  yf[idx] = f2b(v);
}

// ---------------------------------------------------------------------------
extern "C" void kernel_launch(void* const* d_in, const int* in_sizes, int n_in,
                              void* d_out, int out_size, void* d_ws, size_t ws_size,
                              hipStream_t stream)
{
  const float* x       = (const float*)d_in[0];
  const float* Wis     = (const float*)d_in[1];
  const float* Wig     = (const float*)d_in[2];
  const float* conv_w  = (const float*)d_in[3];
  const float* conv_b  = (const float*)d_in[4];
  const float* conv_wb = (const float*)d_in[5];
  const float* conv_bb = (const float*)d_in[6];
  const float* W_dt    = (const float*)d_in[7];
  const float* W_B     = (const float*)d_in[8];
  const float* W_C     = (const float*)d_in[9];
  const float* dtW     = (const float*)d_in[10];
  const float* dtb     = (const float*)d_in[11];
  const float* A_log   = (const float*)d_in[12];
  const float* Dp      = (const float*)d_in[13];
  const float* W_dt_b  = (const float*)d_in[14];
  const float* W_B_b   = (const float*)d_in[15];
  const float* W_C_b   = (const float*)d_in[16];
  const float* dtW_b   = (const float*)d_in[17];
  const float* dtb_b   = (const float*)d_in[18];
  const float* A_log_b = (const float*)d_in[19];
  const float* Dp_b    = (const float*)d_in[20];
  const float* W_out   = (const float*)d_in[21];

  char* ws = (char*)d_ws;
  size_t off = 0;
  auto alloc = [&](size_t bytes) -> char* {
    char* p = ws + off; off += (bytes + 255) & ~(size_t)255; return p;
  };
  u16*   xb    = (u16*)alloc((size_t)ML * DM * 2);
  u16*   wisb  = (u16*)alloc((size_t)DI * DM * 2);
  u16*   wigb  = (u16*)alloc((size_t)DI * DM * 2);
  u16*   woutb = (u16*)alloc((size_t)DM * DI * 2);
  u16*   xsg = (u16*)alloc((size_t)ML * 3072 * 2);     // [xs | silu(z)]
  u16*   xc  = (u16*)alloc((size_t)ML * DI * 2);
  u16*   xcb = (u16*)alloc((size_t)ML * DI * 2);       // reversed space
  u16*   wcf = (u16*)alloc((size_t)128 * DI * 2);      // [B|C|W_dt|0]
  u16*   wcb = (u16*)alloc((size_t)128 * DI * 2);
  u16*   dtwf = (u16*)alloc((size_t)DI * 64 * 2);      // dtW bf16 K-padded
  u16*   dtwb = (u16*)alloc((size_t)DI * 64 * 2);
  float* pf  = (float*)alloc((size_t)ML * 32 * 4);     // [B|C] fp32, ld 32
  float* pb  = (float*)alloc((size_t)ML * 32 * 4);
  u16*   dtlf = (u16*)alloc((size_t)ML * 64 * 2);      // dt_low bf16, ld 64
  u16*   dtlb = (u16*)alloc((size_t)ML * 64 * 2);
  float* df  = (float*)alloc((size_t)ML * DI * 4);     // delta (softplus'd)
  float* db  = (float*)alloc((size_t)ML * DI * 4);
  u16*   yf  = (u16*)alloc((size_t)ML * DI * 2);       // later holds combined y
  u16*   ybr = (u16*)alloc((size_t)ML * DI * 2);       // reversed space
  float* sdl = (float*)alloc((size_t)2 * BB * NSEG * DI * 4);
  float* bs  = (float*)alloc((size_t)2 * BB * NSEG * DI * 16 * 4);
  // total ~110 MB

  // 1. fp32->bf16 conversion + weight packing (wcat, dtWb)
  const int conv_total = SEG_X + 3 * SEG_W + 2 * SEG_CAT + 2 * SEG_DTW;
  convert_kernel<<<(conv_total + 255) / 256, 256, 0, stream>>>(
      (const float4*)x, (const float4*)Wis, (const float4*)Wig, (const float4*)W_out,
      W_B, W_C, W_dt, W_B_b, W_C_b, W_dt_b, dtW, dtW_b,
      (u16x4_t*)xb, (u16x4_t*)wisb, (u16x4_t*)wigb, (u16x4_t*)woutb,
      (u16x4_t*)wcf, (u16x4_t*)wcb, (u16x4_t*)dtwf, (u16x4_t*)dtwb);

  // 2. in-proj: [xs | silu(z)] = x @ [Wis; Wig]^T
  gemm_bt<<<dim3(3072 / 128, ML / 128, 1), 256, 0, stream>>>(
      xb, wisb, wigb, DI, xsg, ML, 3072, DM, 3072, 0,
      nullptr, nullptr, nullptr, nullptr, nullptr, nullptr, nullptr);

  // 3. causal conv + silu (fwd + reversed)
  conv_kernel<<<(ML * DI) / 256, 256, 0, stream>>>(
      xsg, conv_w, conv_b, conv_wb, conv_bb, xc, xcb);

  // 4. proj GEMMs: [B|C fp32 -> pf] + [dt_low bf16 -> dtl] = xc @ wcat^T
  gemm_bt<<<dim3(1, ML / 128, 2), 256, 0, stream>>>(
      xc, wcf, nullptr, 1 << 30, pf, ML, 128, DI, 32, 5,
      xcb, wcb, pb, dtlf, dtlb, nullptr, nullptr);

  // 5. delta GEMM: delta = softplus(dt_low @ dtW^T + dtb), K=64, fp32 out
  gemm_bt<<<dim3(DI / 128, ML / 128, 2), 256, 0, stream>>>(
      dtlf, dtwf, nullptr, 1 << 30, df, ML, DI, 64, DI, 6,
      dtlb, dtwb, db, nullptr, nullptr, dtb, dtb_b);

  // 6. segmented scan: summaries -> carries -> apply
  scan_sum<<<dim3(DI / 256, BB, 2 * NSEG), 256, 0, stream>>>(
      df, db, xc, xcb, pf, pb, A_log, A_log_b, sdl, bs);
  scan_carry<<<(2 * BB * DI * 16) / 256, 256, 0, stream>>>(
      A_log, A_log_b, sdl, bs);
  scan_apply<<<dim3(DI / 256, BB, 2 * NSEG), 256, 0, stream>>>(
      df, db, xc, xcb, pf, pb, A_log, A_log_b, Dp, Dp_b, bs, yf, ybr);

  // 7. gated combine + un-reverse (in place over yf)
  combine_kernel<<<(ML * DI) / 256, 256, 0, stream>>>(ybr, xsg, yf);

  // 8. out-proj: out = yf @ W_out^T, FP32 to d_out
  gemm_bt<<<dim3(DM / 128, ML / 128, 1), 256, 0, stream>>>(
      yf, woutb, nullptr, 1 << 30, d_out, ML, DM, DI, DM, 2,
      nullptr, nullptr, nullptr, nullptr, nullptr, nullptr, nullptr);
}